// Round 1
// baseline (1006.908 us; speedup 1.0000x reference)
//
#include <hip/hip_runtime.h>

#define HIDDEN 128
#define NLAYERS 4

// ---------------- CSR build ----------------

__global__ void hist_kernel(const int* __restrict__ dst, int* __restrict__ counts, int E) {
    int e = blockIdx.x * blockDim.x + threadIdx.x;
    if (e < E) atomicAdd(&counts[dst[e]], 1);
}

// single-block exclusive scan (n up to ~100k), writes offsets[0..n] and wpos[0..n-1]
__global__ __launch_bounds__(1024) void scan_kernel(const int* __restrict__ counts,
                                                    int* __restrict__ offsets,
                                                    int* __restrict__ wpos, int n) {
    __shared__ int buf[1024];
    __shared__ int carry;
    const int t = threadIdx.x;
    if (t == 0) carry = 0;
    __syncthreads();
    for (int base = 0; base < n; base += 1024) {
        int i = base + t;
        int v = (i < n) ? counts[i] : 0;
        buf[t] = v;
        __syncthreads();
        for (int off = 1; off < 1024; off <<= 1) {
            int x = (t >= off) ? buf[t - off] : 0;
            __syncthreads();
            buf[t] += x;
            __syncthreads();
        }
        int incl = buf[t];
        int excl = incl - v + carry;   // reads carry (pre-update)
        if (i < n) { offsets[i] = excl; wpos[i] = excl; }
        __syncthreads();
        if (t == 1023) carry += incl;
        __syncthreads();
    }
    if (t == 0) offsets[n] = carry;
}

__global__ void fill_kernel(const int* __restrict__ src, const int* __restrict__ dst,
                            int* __restrict__ wpos, int* __restrict__ csr_src,
                            int* __restrict__ csr_eid, int E) {
    int e = blockIdx.x * blockDim.x + threadIdx.x;
    if (e < E) {
        int d = dst[e];
        int p = atomicAdd(&wpos[d], 1);
        csr_src[p] = src[e];
        csr_eid[p] = e;
    }
}

// ---------------- per-layer aggregation: z0 = h + sum_in relu(h[src] + ea) ----------------
// one block (128 threads) per node; ea recomputed from edge_attr @ We + be
__global__ __launch_bounds__(128) void agg_kernel(const float* __restrict__ h,
                                                  const int* __restrict__ csr_src,
                                                  const int* __restrict__ csr_eid,
                                                  const float* __restrict__ edge_attr,
                                                  const int* __restrict__ offsets,
                                                  const float* __restrict__ We,
                                                  const float* __restrict__ be,
                                                  float* __restrict__ z0, int n) {
    const int v = blockIdx.x;
    const int c = threadIdx.x;
    float wec[16];
#pragma unroll
    for (int k = 0; k < 16; ++k) wec[k] = We[k * HIDDEN + c];
    const float bec = be[c];

    const int e0 = offsets[v];
    const int e1 = offsets[v + 1];
    float acc = 0.f;
    for (int j = e0; j < e1; ++j) {
        const int s   = csr_src[j];
        const int eid = csr_eid[j];
        const float4* ea4 = (const float4*)(edge_attr + (size_t)eid * 16);
        float4 a0 = ea4[0], a1 = ea4[1], a2 = ea4[2], a3 = ea4[3];
        float m = bec;
        m = fmaf(a0.x, wec[0],  m); m = fmaf(a0.y, wec[1],  m);
        m = fmaf(a0.z, wec[2],  m); m = fmaf(a0.w, wec[3],  m);
        m = fmaf(a1.x, wec[4],  m); m = fmaf(a1.y, wec[5],  m);
        m = fmaf(a1.z, wec[6],  m); m = fmaf(a1.w, wec[7],  m);
        m = fmaf(a2.x, wec[8],  m); m = fmaf(a2.y, wec[9],  m);
        m = fmaf(a2.z, wec[10], m); m = fmaf(a2.w, wec[11], m);
        m = fmaf(a3.x, wec[12], m); m = fmaf(a3.y, wec[13], m);
        m = fmaf(a3.z, wec[14], m); m = fmaf(a3.w, wec[15], m);
        m += h[(size_t)s * HIDDEN + c];
        acc += fmaxf(m, 0.f);
    }
    z0[(size_t)v * HIDDEN + c] = h[(size_t)v * HIDDEN + c] + acc;
}

// ---------------- fused MLP + LayerNorm + residual ----------------
// h = relu(LN(relu(z0@W1+b1)@W2+b2)) + h, in-place on h (d_out)
__global__ __launch_bounds__(256) void mlp_kernel(const float* __restrict__ z0,
                                                  float* __restrict__ h,
                                                  const float* __restrict__ W1,
                                                  const float* __restrict__ b1,
                                                  const float* __restrict__ W2,
                                                  const float* __restrict__ b2,
                                                  const float* __restrict__ lng,
                                                  const float* __restrict__ lnb, int n) {
    __shared__ float rows[32][HIDDEN];      // 16 KB: z0 rows -> t rows -> z2 rows
    __shared__ float wbuf[64 * HIDDEN];     // 32 KB: half-K weight tile
    __shared__ float mu_s[32], rs_s[32];

    const int t  = threadIdx.x;
    const int r0 = blockIdx.x * 32;
    const int c  = t & 127;
    const int rg = t >> 7;                  // 0 or 1 -> row group of 16

    // stage z0 rows
#pragma unroll
    for (int j = 0; j < 16; ++j) {
        int idx = t + j * 256;
        int rr = idx >> 7, cc = idx & 127;
        int gr = r0 + rr;
        rows[rr][cc] = (gr < n) ? z0[(size_t)gr * HIDDEN + cc] : 0.f;
    }

    float acc[16];
    // ---- GEMM1: t = relu(z0 @ W1 + b1) ----
#pragma unroll
    for (int i = 0; i < 16; ++i) acc[i] = 0.f;
    for (int kk = 0; kk < 2; ++kk) {
        __syncthreads();                    // covers rows staging (kk=0) / prior reads (kk=1)
        const float* Wsrc = W1 + kk * 8192;
#pragma unroll
        for (int j = 0; j < 32; ++j) wbuf[t + j * 256] = Wsrc[t + j * 256];
        __syncthreads();
        for (int k = 0; k < 64; k += 4) {
            float w0 = wbuf[(k + 0) * HIDDEN + c];
            float w1 = wbuf[(k + 1) * HIDDEN + c];
            float w2 = wbuf[(k + 2) * HIDDEN + c];
            float w3 = wbuf[(k + 3) * HIDDEN + c];
#pragma unroll
            for (int i = 0; i < 16; ++i) {
                const float4 a = *(const float4*)&rows[rg * 16 + i][kk * 64 + k];
                acc[i] = fmaf(a.x, w0, acc[i]);
                acc[i] = fmaf(a.y, w1, acc[i]);
                acc[i] = fmaf(a.z, w2, acc[i]);
                acc[i] = fmaf(a.w, w3, acc[i]);
            }
        }
    }
    const float b1c = b1[c];
    __syncthreads();                        // all rows reads done before overwrite
#pragma unroll
    for (int i = 0; i < 16; ++i) rows[rg * 16 + i][c] = fmaxf(acc[i] + b1c, 0.f);

    // ---- GEMM2: z2 = t @ W2 + b2 ----
#pragma unroll
    for (int i = 0; i < 16; ++i) acc[i] = 0.f;
    for (int kk = 0; kk < 2; ++kk) {
        __syncthreads();                    // covers t writes (kk=0)
        const float* Wsrc = W2 + kk * 8192;
#pragma unroll
        for (int j = 0; j < 32; ++j) wbuf[t + j * 256] = Wsrc[t + j * 256];
        __syncthreads();
        for (int k = 0; k < 64; k += 4) {
            float w0 = wbuf[(k + 0) * HIDDEN + c];
            float w1 = wbuf[(k + 1) * HIDDEN + c];
            float w2 = wbuf[(k + 2) * HIDDEN + c];
            float w3 = wbuf[(k + 3) * HIDDEN + c];
#pragma unroll
            for (int i = 0; i < 16; ++i) {
                const float4 a = *(const float4*)&rows[rg * 16 + i][kk * 64 + k];
                acc[i] = fmaf(a.x, w0, acc[i]);
                acc[i] = fmaf(a.y, w1, acc[i]);
                acc[i] = fmaf(a.z, w2, acc[i]);
                acc[i] = fmaf(a.w, w3, acc[i]);
            }
        }
    }
    const float b2c = b2[c];
    __syncthreads();
#pragma unroll
    for (int i = 0; i < 16; ++i) rows[rg * 16 + i][c] = acc[i] + b2c;
    __syncthreads();

    // ---- LayerNorm stats (two-pass for accuracy) ----
    {
        const int rr = t >> 3, j = t & 7;   // 8 threads per row
        float s = 0.f;
#pragma unroll
        for (int q = 0; q < 16; ++q) s += rows[rr][j * 16 + q];
#pragma unroll
        for (int off = 1; off < 8; off <<= 1) s += __shfl_xor(s, off, 64);
        const float mu = s * (1.f / 128.f);
        float d2 = 0.f;
#pragma unroll
        for (int q = 0; q < 16; ++q) {
            float d = rows[rr][j * 16 + q] - mu;
            d2 = fmaf(d, d, d2);
        }
#pragma unroll
        for (int off = 1; off < 8; off <<= 1) d2 += __shfl_xor(d2, off, 64);
        if (j == 0) {
            mu_s[rr] = mu;
            rs_s[rr] = rsqrtf(d2 * (1.f / 128.f) + 1e-5f);
        }
    }
    __syncthreads();

    // ---- epilogue: h = relu(LN(z2)) + h ----
#pragma unroll
    for (int j = 0; j < 16; ++j) {
        int idx = t + j * 256;
        int rr = idx >> 7, cc = idx & 127;
        int gr = r0 + rr;
        if (gr < n) {
            float v = rows[rr][cc];
            float y = (v - mu_s[rr]) * rs_s[rr] * lng[cc] + lnb[cc];
            size_t o = (size_t)gr * HIDDEN + cc;
            h[o] = fmaxf(y, 0.f) + h[o];
        }
    }
}

// ---------------- launch ----------------

extern "C" void kernel_launch(void* const* d_in, const int* in_sizes, int n_in,
                              void* d_out, int out_size, void* d_ws, size_t ws_size,
                              hipStream_t stream) {
    const float* x     = (const float*)d_in[0];
    const int*   ei    = (const int*)d_in[2];
    const float* eattr = (const float*)d_in[3];
    const float* We    = (const float*)d_in[4];
    const float* be    = (const float*)d_in[5];
    const float* W1    = (const float*)d_in[6];
    const float* b1    = (const float*)d_in[7];
    const float* W2    = (const float*)d_in[8];
    const float* b2    = (const float*)d_in[9];
    const float* lng   = (const float*)d_in[10];
    const float* lnb   = (const float*)d_in[11];
    float* h = (float*)d_out;

    const int n = in_sizes[0] / HIDDEN;
    const int E = in_sizes[2] / 2;
    const int* src = ei;
    const int* dst = ei + E;

    size_t off = 0;
    auto take = [&](size_t bytes) {
        void* p = (char*)d_ws + off;
        off += (bytes + 255) & ~(size_t)255;
        return p;
    };
    float* z0      = (float*)take((size_t)n * HIDDEN * 4);
    int*   counts  = (int*)take((size_t)n * 4);
    int*   offsets = (int*)take(((size_t)n + 1) * 4);
    int*   wpos    = (int*)take((size_t)n * 4);
    int*   csr_src = (int*)take((size_t)E * 4);
    int*   csr_eid = (int*)take((size_t)E * 4);

    // h <- x
    hipMemcpyAsync(h, x, (size_t)n * HIDDEN * 4, hipMemcpyDeviceToDevice, stream);

    // CSR build (once per launch)
    hipMemsetAsync(counts, 0, (size_t)n * 4, stream);
    int eb = (E + 255) / 256;
    hist_kernel<<<eb, 256, 0, stream>>>(dst, counts, E);
    scan_kernel<<<1, 1024, 0, stream>>>(counts, offsets, wpos, n);
    fill_kernel<<<eb, 256, 0, stream>>>(src, dst, wpos, csr_src, csr_eid, E);

    for (int l = 0; l < NLAYERS; ++l) {
        agg_kernel<<<n, 128, 0, stream>>>(h, csr_src, csr_eid, eattr, offsets,
                                          We, be, z0, n);
        mlp_kernel<<<(n + 31) / 32, 256, 0, stream>>>(z0, h,
                                                      W1 + (size_t)l * HIDDEN * HIDDEN,
                                                      b1 + (size_t)l * HIDDEN,
                                                      W2 + (size_t)l * HIDDEN * HIDDEN,
                                                      b2 + (size_t)l * HIDDEN,
                                                      lng + (size_t)l * HIDDEN,
                                                      lnb + (size_t)l * HIDDEN, n);
    }
}

// Round 2
// 773.210 us; speedup vs baseline: 1.3022x; 1.3022x over previous
//
#include <hip/hip_runtime.h>

#define HIDDEN 128
#define NLAYERS 4

typedef __attribute__((ext_vector_type(8))) short short8;
typedef __attribute__((ext_vector_type(4))) float f32x4;

__device__ __forceinline__ ushort f2bf(float f) {
    uint x = __builtin_bit_cast(uint, f);
    return (ushort)((x + 0x7fffu + ((x >> 16) & 1u)) >> 16);
}
__device__ __forceinline__ float bf2f(ushort u) {
    uint x = ((uint)u) << 16;
    return __builtin_bit_cast(float, x);
}

// ---------------- CSR build ----------------

__global__ void hist_kernel(const int* __restrict__ dst, int* __restrict__ counts, int E) {
    int e = blockIdx.x * blockDim.x + threadIdx.x;
    if (e < E) atomicAdd(&counts[dst[e]], 1);
}

// single-block scan via wave shuffles (2 barriers per 1024 chunk instead of 20)
__global__ __launch_bounds__(1024) void scan_kernel(const int* __restrict__ counts,
                                                    int* __restrict__ offsets,
                                                    int* __restrict__ wpos, int n) {
    __shared__ int wsum[16];
    __shared__ int carry_s;
    const int t = threadIdx.x, wv = t >> 6, ln = t & 63;
    if (t == 0) carry_s = 0;
    __syncthreads();
    for (int base = 0; base < n; base += 1024) {
        int i = base + t;
        int v = (i < n) ? counts[i] : 0;
        int s = v;
#pragma unroll
        for (int off = 1; off < 64; off <<= 1) {
            int x = __shfl_up(s, off, 64);
            if (ln >= off) s += x;
        }
        if (ln == 63) wsum[wv] = s;
        __syncthreads();
        if (t < 16) {
            int x = wsum[t];
#pragma unroll
            for (int off = 1; off < 16; off <<= 1) {
                int y = __shfl_up(x, off, 16);
                if ((t & 15) >= off) x += y;
            }
            wsum[t] = x;  // inclusive wave sums
        }
        __syncthreads();
        int wbase = (wv ? wsum[wv - 1] : 0) + carry_s;
        int excl = wbase + s - v;
        if (i < n) { offsets[i] = excl; wpos[i] = excl; }
        __syncthreads();                  // wsum/carry reads done
        if (t == 0) carry_s += wsum[15];
        __syncthreads();
    }
    if (t == 0) offsets[n] = carry_s;
}

__global__ void fill_kernel(const int* __restrict__ src, const int* __restrict__ dst,
                            int* __restrict__ wpos, int2* __restrict__ csr, int E) {
    int e = blockIdx.x * blockDim.x + threadIdx.x;
    if (e < E) {
        int d = dst[e];
        int p = atomicAdd(&wpos[d], 1);
        csr[p] = make_int2(src[e], e);
    }
}

// ---------------- init / weight prep ----------------

__global__ void h16init_kernel(const float* __restrict__ x, ushort* __restrict__ h16, int total4) {
    int i = blockIdx.x * blockDim.x + threadIdx.x;
    if (i < total4) {
        float4 v = ((const float4*)x)[i];
        uint2 o;
        o.x = (uint)f2bf(v.x) | ((uint)f2bf(v.y) << 16);
        o.y = (uint)f2bf(v.z) | ((uint)f2bf(v.w) << 16);
        ((uint2*)h16)[i] = o;
    }
}

// Wt[(l*2+m)][n][k] = bf16(W{m}[l][k][n])  -- transposed, B^T layout for MFMA
__global__ void wconv_kernel(const float* __restrict__ W1, const float* __restrict__ W2,
                             ushort* __restrict__ Wt) {
    int i = blockIdx.x * blockDim.x + threadIdx.x;  // < 4*2*128*128
    int l = i >> 15;
    int m = (i >> 14) & 1;
    int nn = (i >> 7) & 127;
    int kk = i & 127;
    const float* W = m ? W2 : W1;
    Wt[i] = f2bf(W[l * 16384 + kk * 128 + nn]);
}

// ---------------- aggregation: z0 = bf16(h32 + sum_in relu(h16[src] + ea)) ----------------
// 2 nodes per block; one wave per node; thread = 2 channels
__global__ __launch_bounds__(128) void agg_kernel(const ushort* __restrict__ h16,
                                                  const float* __restrict__ h32,
                                                  const int2* __restrict__ csr,
                                                  const float* __restrict__ edge_attr,
                                                  const int* __restrict__ offsets,
                                                  const float* __restrict__ We,
                                                  const float* __restrict__ be,
                                                  ushort* __restrict__ z0, int n) {
    const int v = blockIdx.x * 2 + (threadIdx.x >> 6);
    if (v >= n) return;
    const int t = threadIdx.x & 63;
    const int c0 = t * 2;
    float2 wec[16];
#pragma unroll
    for (int k = 0; k < 16; ++k) wec[k] = *(const float2*)(We + k * HIDDEN + c0);
    const float2 bec = *(const float2*)(be + c0);

    const int e0 = offsets[v], e1 = offsets[v + 1];
    float a0 = 0.f, a1 = 0.f;
    for (int j = e0; j < e1; ++j) {
        int2 se = csr[j];
        const float4* ea4 = (const float4*)(edge_attr + (size_t)se.y * 16);
        float4 q0 = ea4[0], q1 = ea4[1], q2 = ea4[2], q3 = ea4[3];
        float m0 = bec.x, m1 = bec.y;
        m0 = fmaf(q0.x, wec[0].x, m0);  m1 = fmaf(q0.x, wec[0].y, m1);
        m0 = fmaf(q0.y, wec[1].x, m0);  m1 = fmaf(q0.y, wec[1].y, m1);
        m0 = fmaf(q0.z, wec[2].x, m0);  m1 = fmaf(q0.z, wec[2].y, m1);
        m0 = fmaf(q0.w, wec[3].x, m0);  m1 = fmaf(q0.w, wec[3].y, m1);
        m0 = fmaf(q1.x, wec[4].x, m0);  m1 = fmaf(q1.x, wec[4].y, m1);
        m0 = fmaf(q1.y, wec[5].x, m0);  m1 = fmaf(q1.y, wec[5].y, m1);
        m0 = fmaf(q1.z, wec[6].x, m0);  m1 = fmaf(q1.z, wec[6].y, m1);
        m0 = fmaf(q1.w, wec[7].x, m0);  m1 = fmaf(q1.w, wec[7].y, m1);
        m0 = fmaf(q2.x, wec[8].x, m0);  m1 = fmaf(q2.x, wec[8].y, m1);
        m0 = fmaf(q2.y, wec[9].x, m0);  m1 = fmaf(q2.y, wec[9].y, m1);
        m0 = fmaf(q2.z, wec[10].x, m0); m1 = fmaf(q2.z, wec[10].y, m1);
        m0 = fmaf(q2.w, wec[11].x, m0); m1 = fmaf(q2.w, wec[11].y, m1);
        m0 = fmaf(q3.x, wec[12].x, m0); m1 = fmaf(q3.x, wec[12].y, m1);
        m0 = fmaf(q3.y, wec[13].x, m0); m1 = fmaf(q3.y, wec[13].y, m1);
        m0 = fmaf(q3.z, wec[14].x, m0); m1 = fmaf(q3.z, wec[14].y, m1);
        m0 = fmaf(q3.w, wec[15].x, m0); m1 = fmaf(q3.w, wec[15].y, m1);
        uint hh = *(const uint*)(h16 + (size_t)se.x * HIDDEN + c0);
        a0 += fmaxf(m0 + bf2f((ushort)(hh & 0xffffu)), 0.f);
        a1 += fmaxf(m1 + bf2f((ushort)(hh >> 16)), 0.f);
    }
    const float2 hv = *(const float2*)(h32 + (size_t)v * HIDDEN + c0);
    uint out = (uint)f2bf(hv.x + a0) | ((uint)f2bf(hv.y + a1) << 16);
    *(uint*)(z0 + (size_t)v * HIDDEN + c0) = out;
}

// ---------------- fused MFMA MLP + in-register LayerNorm + residual ----------------
// 64 rows/block, 4 waves (16 rows each), N=K=128.
__global__ __launch_bounds__(256, 3) void mlp_kernel(const ushort* __restrict__ z0,
                                                     float* __restrict__ h32,
                                                     ushort* __restrict__ h16,
                                                     const ushort* __restrict__ W1t,
                                                     const ushort* __restrict__ W2t,
                                                     const float* __restrict__ b1,
                                                     const float* __restrict__ b2,
                                                     const float* __restrict__ lng,
                                                     const float* __restrict__ lnb, int n) {
    __shared__ char smem[49152];  // [0,32K): weights (swizzled bf16) ; [32K,48K): act
    const int t = threadIdx.x, l = t & 63, w = t >> 6;
    const int lm = l & 15, lg = l >> 4;
    const int r0 = blockIdx.x * 64;

    // stage W1 swizzled: chunk idx -> row n=idx>>4; byte = idx*16 ^ ((n&7)<<4)
#pragma unroll
    for (int j = 0; j < 8; ++j) {
        int idx = t + j * 256;
        int byte = (idx * 16) ^ (((idx >> 4) & 7) << 4);
        *(short8*)(smem + byte) = *(const short8*)(W1t + idx * 8);
    }

    float b1v[8], b2v[8], lngv[8], lnbv[8];
#pragma unroll
    for (int nt = 0; nt < 8; ++nt) {
        int col = nt * 16 + lm;
        b1v[nt] = b1[col]; b2v[nt] = b2[col];
        lngv[nt] = lng[col]; lnbv[nt] = lnb[col];
    }

    // A frags straight from global z0 (bf16x8, 16B aligned)
    short8 a[4];
    {
        int arow = r0 + w * 16 + lm;
        if (arow >= n) arow = n - 1;
        const ushort* zp = z0 + (size_t)arow * HIDDEN + lg * 8;
#pragma unroll
        for (int kk = 0; kk < 4; ++kk) a[kk] = *(const short8*)(zp + kk * 32);
    }
    __syncthreads();

    // GEMM1
    f32x4 acc[8];
#pragma unroll
    for (int nt = 0; nt < 8; ++nt) {
        f32x4 c = {0.f, 0.f, 0.f, 0.f};
#pragma unroll
        for (int kk = 0; kk < 4; ++kk) {
            int nrow = nt * 16 + lm;
            int byte = (nrow * 256 + kk * 64 + lg * 16) ^ ((nrow & 7) << 4);
            short8 b = *(const short8*)(smem + byte);
            c = __builtin_amdgcn_mfma_f32_16x16x32_bf16(a[kk], b, c, 0, 0, 0);
        }
        acc[nt] = c;
    }

    // bias + relu, D-layout -> act (swizzled bf16) for GEMM2 A-frag reads
#pragma unroll
    for (int nt = 0; nt < 8; ++nt) {
        int col = nt * 16 + lm;
#pragma unroll
        for (int j = 0; j < 4; ++j) {
            int rw = w * 16 + lg * 4 + j;
            int byte = (rw * 256 + col * 2) ^ ((rw & 7) << 4);
            *(ushort*)(smem + 32768 + byte) = f2bf(fmaxf(acc[nt][j] + b1v[nt], 0.f));
        }
    }
    __syncthreads();  // act complete, all W1 reads complete

    // stage W2 over W1 region; concurrently read A2 frags from act region
#pragma unroll
    for (int j = 0; j < 8; ++j) {
        int idx = t + j * 256;
        int byte = (idx * 16) ^ (((idx >> 4) & 7) << 4);
        *(short8*)(smem + byte) = *(const short8*)(W2t + idx * 8);
    }
    short8 a2[4];
    {
        int rw = w * 16 + lm;
#pragma unroll
        for (int kk = 0; kk < 4; ++kk) {
            int byte = (rw * 256 + kk * 64 + lg * 16) ^ ((rw & 7) << 4);
            a2[kk] = *(const short8*)(smem + 32768 + byte);
        }
    }
    __syncthreads();  // W2 staged

    // GEMM2
    f32x4 acc2[8];
#pragma unroll
    for (int nt = 0; nt < 8; ++nt) {
        f32x4 c = {0.f, 0.f, 0.f, 0.f};
#pragma unroll
        for (int kk = 0; kk < 4; ++kk) {
            int nrow = nt * 16 + lm;
            int byte = (nrow * 256 + kk * 64 + lg * 16) ^ ((nrow & 7) << 4);
            short8 b = *(const short8*)(smem + byte);
            c = __builtin_amdgcn_mfma_f32_16x16x32_bf16(a2[kk], b, c, 0, 0, 0);
        }
        acc2[nt] = c;
    }

    // + b2, then in-register LayerNorm.
    // D layout: lane holds rows rw = w*16 + lg*4 + j (j=0..3), cols nt*16+lm.
    // Row rw lives in the 16 contiguous lanes sharing lg -> shfl_xor 1/2/4/8.
    float val[8][4];
#pragma unroll
    for (int nt = 0; nt < 8; ++nt)
#pragma unroll
        for (int j = 0; j < 4; ++j) val[nt][j] = acc2[nt][j] + b2v[nt];

    float mu[4], rs[4];
#pragma unroll
    for (int j = 0; j < 4; ++j) {
        float s = 0.f;
#pragma unroll
        for (int nt = 0; nt < 8; ++nt) s += val[nt][j];
        s += __shfl_xor(s, 1, 64); s += __shfl_xor(s, 2, 64);
        s += __shfl_xor(s, 4, 64); s += __shfl_xor(s, 8, 64);
        mu[j] = s * (1.f / 128.f);
        float d2 = 0.f;
#pragma unroll
        for (int nt = 0; nt < 8; ++nt) {
            float d = val[nt][j] - mu[j];
            d2 = fmaf(d, d, d2);
        }
        d2 += __shfl_xor(d2, 1, 64); d2 += __shfl_xor(d2, 2, 64);
        d2 += __shfl_xor(d2, 4, 64); d2 += __shfl_xor(d2, 8, 64);
        rs[j] = rsqrtf(d2 * (1.f / 128.f) + 1e-5f);
    }

    // epilogue: h = relu(LN(z2)) + h ; maintain bf16 mirror
#pragma unroll
    for (int j = 0; j < 4; ++j) {
        int grow = r0 + w * 16 + lg * 4 + j;
        if (grow < n) {
#pragma unroll
            for (int nt = 0; nt < 8; ++nt) {
                int col = nt * 16 + lm;
                size_t o = (size_t)grow * HIDDEN + col;
                float y = fmaxf((val[nt][j] - mu[j]) * rs[j] * lngv[nt] + lnbv[nt], 0.f) + h32[o];
                h32[o] = y;
                h16[o] = f2bf(y);
            }
        }
    }
}

// ---------------- launch ----------------

extern "C" void kernel_launch(void* const* d_in, const int* in_sizes, int n_in,
                              void* d_out, int out_size, void* d_ws, size_t ws_size,
                              hipStream_t stream) {
    const float* x     = (const float*)d_in[0];
    const int*   ei    = (const int*)d_in[2];
    const float* eattr = (const float*)d_in[3];
    const float* We    = (const float*)d_in[4];
    const float* be    = (const float*)d_in[5];
    const float* W1    = (const float*)d_in[6];
    const float* b1    = (const float*)d_in[7];
    const float* W2    = (const float*)d_in[8];
    const float* b2    = (const float*)d_in[9];
    const float* lng   = (const float*)d_in[10];
    const float* lnb   = (const float*)d_in[11];
    float* h32 = (float*)d_out;

    const int n = in_sizes[0] / HIDDEN;
    const int E = in_sizes[2] / 2;
    const int* src = ei;
    const int* dst = ei + E;

    size_t off = 0;
    auto take = [&](size_t bytes) {
        void* p = (char*)d_ws + off;
        off += (bytes + 255) & ~(size_t)255;
        return p;
    };
    ushort* z0      = (ushort*)take((size_t)n * HIDDEN * 2);
    ushort* h16     = (ushort*)take((size_t)n * HIDDEN * 2);
    ushort* Wt      = (ushort*)take((size_t)NLAYERS * 2 * HIDDEN * HIDDEN * 2);
    int*    counts  = (int*)take((size_t)n * 4);
    int*    offsets = (int*)take(((size_t)n + 1) * 4);
    int*    wpos    = (int*)take((size_t)n * 4);
    int2*   csr     = (int2*)take((size_t)E * 8);

    hipMemcpyAsync(h32, x, (size_t)n * HIDDEN * 4, hipMemcpyDeviceToDevice, stream);
    h16init_kernel<<<((n * HIDDEN / 4) + 255) / 256, 256, 0, stream>>>(x, h16, n * HIDDEN / 4);
    wconv_kernel<<<(NLAYERS * 2 * HIDDEN * HIDDEN) / 256, 256, 0, stream>>>(W1, W2, Wt);

    hipMemsetAsync(counts, 0, (size_t)n * 4, stream);
    int eb = (E + 255) / 256;
    hist_kernel<<<eb, 256, 0, stream>>>(dst, counts, E);
    scan_kernel<<<1, 1024, 0, stream>>>(counts, offsets, wpos, n);
    fill_kernel<<<eb, 256, 0, stream>>>(src, dst, wpos, csr, E);

    for (int lyr = 0; lyr < NLAYERS; ++lyr) {
        agg_kernel<<<(n + 1) / 2, 128, 0, stream>>>(h16, h32, csr, eattr, offsets,
                                                    We, be, z0, n);
        mlp_kernel<<<(n + 63) / 64, 256, 0, stream>>>(z0, h32, h16,
                                                      Wt + (size_t)(lyr * 2 + 0) * 16384,
                                                      Wt + (size_t)(lyr * 2 + 1) * 16384,
                                                      b1 + (size_t)lyr * HIDDEN,
                                                      b2 + (size_t)lyr * HIDDEN,
                                                      lng + (size_t)lyr * HIDDEN,
                                                      lnb + (size_t)lyr * HIDDEN, n);
    }
}

// Round 3
// 521.960 us; speedup vs baseline: 1.9291x; 1.4814x over previous
//
#include <hip/hip_runtime.h>

#define HIDDEN 128
#define NLAYERS 4

typedef __attribute__((ext_vector_type(8))) short short8;
typedef __attribute__((ext_vector_type(4))) float f32x4;

__device__ __forceinline__ ushort f2bf(float f) {
    uint x = __builtin_bit_cast(uint, f);
    return (ushort)((x + 0x7fffu + ((x >> 16) & 1u)) >> 16);
}
__device__ __forceinline__ float bf2f(ushort u) {
    uint x = ((uint)u) << 16;
    return __builtin_bit_cast(float, x);
}

// ---------------- CSR build ----------------

__global__ void hist_kernel(const int* __restrict__ dst, int* __restrict__ counts, int E) {
    int e = blockIdx.x * blockDim.x + threadIdx.x;
    if (e < E) atomicAdd(&counts[dst[e]], 1);
}

__global__ __launch_bounds__(1024) void scan_kernel(const int* __restrict__ counts,
                                                    int* __restrict__ offsets,
                                                    int* __restrict__ wpos, int n) {
    __shared__ int wsum[16];
    __shared__ int carry_s;
    const int t = threadIdx.x, wv = t >> 6, ln = t & 63;
    if (t == 0) carry_s = 0;
    __syncthreads();
    for (int base = 0; base < n; base += 1024) {
        int i = base + t;
        int v = (i < n) ? counts[i] : 0;
        int s = v;
#pragma unroll
        for (int off = 1; off < 64; off <<= 1) {
            int x = __shfl_up(s, off, 64);
            if (ln >= off) s += x;
        }
        if (ln == 63) wsum[wv] = s;
        __syncthreads();
        if (t < 16) {
            int x = wsum[t];
#pragma unroll
            for (int off = 1; off < 16; off <<= 1) {
                int y = __shfl_up(x, off, 16);
                if ((t & 15) >= off) x += y;
            }
            wsum[t] = x;
        }
        __syncthreads();
        int wbase = (wv ? wsum[wv - 1] : 0) + carry_s;
        int excl = wbase + s - v;
        if (i < n) { offsets[i] = excl; wpos[i] = excl; }
        __syncthreads();
        if (t == 0) carry_s += wsum[15];
        __syncthreads();
    }
    if (t == 0) offsets[n] = carry_s;
}

__global__ void fill_kernel(const int* __restrict__ src, const int* __restrict__ dst,
                            int* __restrict__ wpos, int2* __restrict__ csr, int E) {
    int e = blockIdx.x * blockDim.x + threadIdx.x;
    if (e < E) {
        int d = dst[e];
        int p = atomicAdd(&wpos[d], 1);
        csr[p] = make_int2(src[e], e);
    }
}

// ---------------- init / weight prep ----------------

__global__ void h16init_kernel(const float* __restrict__ x, ushort* __restrict__ h16, int total4) {
    int i = blockIdx.x * blockDim.x + threadIdx.x;
    if (i < total4) {
        float4 v = ((const float4*)x)[i];
        uint2 o;
        o.x = (uint)f2bf(v.x) | ((uint)f2bf(v.y) << 16);
        o.y = (uint)f2bf(v.z) | ((uint)f2bf(v.w) << 16);
        ((uint2*)h16)[i] = o;
    }
}

__global__ void wconv_kernel(const float* __restrict__ W1, const float* __restrict__ W2,
                             ushort* __restrict__ Wt) {
    int i = blockIdx.x * blockDim.x + threadIdx.x;  // < 4*2*128*128
    int l = i >> 15;
    int m = (i >> 14) & 1;
    int nn = (i >> 7) & 127;
    int kk = i & 127;
    const float* W = m ? W2 : W1;
    Wt[i] = f2bf(W[l * 16384 + kk * 128 + nn]);
}

#define EA_FMA16(q0, q1, q2, q3)                                          \
    m0 = fmaf(q0.x, wec[0].x, m0);  m1 = fmaf(q0.x, wec[0].y, m1);        \
    m0 = fmaf(q0.y, wec[1].x, m0);  m1 = fmaf(q0.y, wec[1].y, m1);        \
    m0 = fmaf(q0.z, wec[2].x, m0);  m1 = fmaf(q0.z, wec[2].y, m1);        \
    m0 = fmaf(q0.w, wec[3].x, m0);  m1 = fmaf(q0.w, wec[3].y, m1);        \
    m0 = fmaf(q1.x, wec[4].x, m0);  m1 = fmaf(q1.x, wec[4].y, m1);        \
    m0 = fmaf(q1.y, wec[5].x, m0);  m1 = fmaf(q1.y, wec[5].y, m1);        \
    m0 = fmaf(q1.z, wec[6].x, m0);  m1 = fmaf(q1.z, wec[6].y, m1);        \
    m0 = fmaf(q1.w, wec[7].x, m0);  m1 = fmaf(q1.w, wec[7].y, m1);        \
    m0 = fmaf(q2.x, wec[8].x, m0);  m1 = fmaf(q2.x, wec[8].y, m1);        \
    m0 = fmaf(q2.y, wec[9].x, m0);  m1 = fmaf(q2.y, wec[9].y, m1);        \
    m0 = fmaf(q2.z, wec[10].x, m0); m1 = fmaf(q2.z, wec[10].y, m1);       \
    m0 = fmaf(q2.w, wec[11].x, m0); m1 = fmaf(q2.w, wec[11].y, m1);       \
    m0 = fmaf(q3.x, wec[12].x, m0); m1 = fmaf(q3.x, wec[12].y, m1);       \
    m0 = fmaf(q3.y, wec[13].x, m0); m1 = fmaf(q3.y, wec[13].y, m1);       \
    m0 = fmaf(q3.z, wec[14].x, m0); m1 = fmaf(q3.z, wec[14].y, m1);       \
    m0 = fmaf(q3.w, wec[15].x, m0); m1 = fmaf(q3.w, wec[15].y, m1)

// ---------------- ea precompute (CSR order): ea_csr[p] = bf16(edge_attr[eid]@We + be) ----------------
// block = 256 threads; handles 256 CSR positions; edge_attr rows staged in LDS
__global__ __launch_bounds__(256) void ea_kernel(const int2* __restrict__ csr,
                                                 const float* __restrict__ edge_attr,
                                                 const float* __restrict__ We,
                                                 const float* __restrict__ be,
                                                 ushort* __restrict__ ea_csr, int E) {
    __shared__ int eids[256];
    __shared__ float4 ear[256][4];
    const int t = threadIdx.x, l = t & 63, w = t >> 6;
    const int c0 = l * 2;
    float2 wec[16];
#pragma unroll
    for (int k = 0; k < 16; ++k) wec[k] = *(const float2*)(We + k * HIDDEN + c0);
    const float2 bec = *(const float2*)(be + c0);
    const int p0 = blockIdx.x * 256;

    eids[t] = (p0 + t < E) ? csr[p0 + t].y : 0;
    __syncthreads();
#pragma unroll
    for (int k = 0; k < 4; ++k) {
        int e = (t >> 2) + k * 64;
        int part = t & 3;
        if (p0 + e < E)
            ear[e][part] = ((const float4*)edge_attr)[(size_t)eids[e] * 4 + part];
    }
    __syncthreads();

    for (int j = 0; j < 64; ++j) {
        int e = w * 64 + j;
        int p = p0 + e;
        if (p >= E) break;
        float4 q0 = ear[e][0], q1 = ear[e][1], q2 = ear[e][2], q3 = ear[e][3];
        float m0 = bec.x, m1 = bec.y;
        EA_FMA16(q0, q1, q2, q3);
        uint out = (uint)f2bf(m0) | ((uint)f2bf(m1) << 16);
        *(uint*)(ea_csr + (size_t)p * HIDDEN + c0) = out;
    }
}

// ---------------- aggregation (stream): z0 = bf16(h32 + sum_in relu(h16[src] + ea_csr)) ----------------
// 4 nodes/block, one wave per node, lane = 2 channels
__global__ __launch_bounds__(256) void agg_kernel(const ushort* __restrict__ h16,
                                                  const float* __restrict__ h32,
                                                  const int2* __restrict__ csr,
                                                  const ushort* __restrict__ ea_csr,
                                                  const int* __restrict__ offsets,
                                                  ushort* __restrict__ z0, int n) {
    const int v = blockIdx.x * 4 + (threadIdx.x >> 6);
    if (v >= n) return;
    const int l = threadIdx.x & 63;
    const int c0 = l * 2;

    const int e0 = offsets[v], e1 = offsets[v + 1];
    float a0 = 0.f, a1 = 0.f;
    for (int base = e0; base < e1; base += 64) {
        const int cnt = min(64, e1 - base);
        int sidx = (l < cnt) ? csr[base + l].x : 0;
#pragma unroll 4
        for (int j = 0; j < cnt; ++j) {
            int s = __shfl(sidx, j, 64);
            uint ev = *(const uint*)(ea_csr + ((size_t)(base + j) * HIDDEN) + c0);
            uint hv = *(const uint*)(h16 + ((size_t)s * HIDDEN) + c0);
            float s0 = bf2f((ushort)(ev & 0xffffu)) + bf2f((ushort)(hv & 0xffffu));
            float s1 = bf2f((ushort)(ev >> 16)) + bf2f((ushort)(hv >> 16));
            a0 += fmaxf(s0, 0.f);
            a1 += fmaxf(s1, 0.f);
        }
    }
    const float2 hv2 = *(const float2*)(h32 + (size_t)v * HIDDEN + c0);
    uint out = (uint)f2bf(hv2.x + a0) | ((uint)f2bf(hv2.y + a1) << 16);
    *(uint*)(z0 + (size_t)v * HIDDEN + c0) = out;
}

// ---------------- fallback aggregation (recompute ea per edge) ----------------
__global__ __launch_bounds__(128) void agg_fb_kernel(const ushort* __restrict__ h16,
                                                     const float* __restrict__ h32,
                                                     const int2* __restrict__ csr,
                                                     const float* __restrict__ edge_attr,
                                                     const int* __restrict__ offsets,
                                                     const float* __restrict__ We,
                                                     const float* __restrict__ be,
                                                     ushort* __restrict__ z0, int n) {
    const int v = blockIdx.x * 2 + (threadIdx.x >> 6);
    if (v >= n) return;
    const int t = threadIdx.x & 63;
    const int c0 = t * 2;
    float2 wec[16];
#pragma unroll
    for (int k = 0; k < 16; ++k) wec[k] = *(const float2*)(We + k * HIDDEN + c0);
    const float2 bec = *(const float2*)(be + c0);

    const int e0 = offsets[v], e1 = offsets[v + 1];
    float a0 = 0.f, a1 = 0.f;
    for (int j = e0; j < e1; ++j) {
        int2 se = csr[j];
        const float4* ea4 = (const float4*)(edge_attr + (size_t)se.y * 16);
        float4 q0 = ea4[0], q1 = ea4[1], q2 = ea4[2], q3 = ea4[3];
        float m0 = bec.x, m1 = bec.y;
        EA_FMA16(q0, q1, q2, q3);
        uint hh = *(const uint*)(h16 + (size_t)se.x * HIDDEN + c0);
        a0 += fmaxf(m0 + bf2f((ushort)(hh & 0xffffu)), 0.f);
        a1 += fmaxf(m1 + bf2f((ushort)(hh >> 16)), 0.f);
    }
    const float2 hv = *(const float2*)(h32 + (size_t)v * HIDDEN + c0);
    uint out = (uint)f2bf(hv.x + a0) | ((uint)f2bf(hv.y + a1) << 16);
    *(uint*)(z0 + (size_t)v * HIDDEN + c0) = out;
}

// ---------------- fused MFMA MLP + in-register LayerNorm + residual ----------------
__global__ __launch_bounds__(256, 3) void mlp_kernel(const ushort* __restrict__ z0,
                                                     float* __restrict__ h32,
                                                     ushort* __restrict__ h16,
                                                     const ushort* __restrict__ W1t,
                                                     const ushort* __restrict__ W2t,
                                                     const float* __restrict__ b1,
                                                     const float* __restrict__ b2,
                                                     const float* __restrict__ lng,
                                                     const float* __restrict__ lnb, int n) {
    __shared__ char smem[49152];  // [0,32K): weights (swizzled bf16) ; [32K,48K): act
    const int t = threadIdx.x, l = t & 63, w = t >> 6;
    const int lm = l & 15, lg = l >> 4;
    const int r0 = blockIdx.x * 64;

#pragma unroll
    for (int j = 0; j < 8; ++j) {
        int idx = t + j * 256;
        int byte = (idx * 16) ^ (((idx >> 4) & 7) << 4);
        *(short8*)(smem + byte) = *(const short8*)(W1t + idx * 8);
    }

    float b1v[8], b2v[8], lngv[8], lnbv[8];
#pragma unroll
    for (int nt = 0; nt < 8; ++nt) {
        int col = nt * 16 + lm;
        b1v[nt] = b1[col]; b2v[nt] = b2[col];
        lngv[nt] = lng[col]; lnbv[nt] = lnb[col];
    }

    short8 a[4];
    {
        int arow = r0 + w * 16 + lm;
        if (arow >= n) arow = n - 1;
        const ushort* zp = z0 + (size_t)arow * HIDDEN + lg * 8;
#pragma unroll
        for (int kk = 0; kk < 4; ++kk) a[kk] = *(const short8*)(zp + kk * 32);
    }
    __syncthreads();

    f32x4 acc[8];
#pragma unroll
    for (int nt = 0; nt < 8; ++nt) {
        f32x4 c = {0.f, 0.f, 0.f, 0.f};
#pragma unroll
        for (int kk = 0; kk < 4; ++kk) {
            int nrow = nt * 16 + lm;
            int byte = (nrow * 256 + kk * 64 + lg * 16) ^ ((nrow & 7) << 4);
            short8 b = *(const short8*)(smem + byte);
            c = __builtin_amdgcn_mfma_f32_16x16x32_bf16(a[kk], b, c, 0, 0, 0);
        }
        acc[nt] = c;
    }

#pragma unroll
    for (int nt = 0; nt < 8; ++nt) {
        int col = nt * 16 + lm;
#pragma unroll
        for (int j = 0; j < 4; ++j) {
            int rw = w * 16 + lg * 4 + j;
            int byte = (rw * 256 + col * 2) ^ ((rw & 7) << 4);
            *(ushort*)(smem + 32768 + byte) = f2bf(fmaxf(acc[nt][j] + b1v[nt], 0.f));
        }
    }
    __syncthreads();

#pragma unroll
    for (int j = 0; j < 8; ++j) {
        int idx = t + j * 256;
        int byte = (idx * 16) ^ (((idx >> 4) & 7) << 4);
        *(short8*)(smem + byte) = *(const short8*)(W2t + idx * 8);
    }
    short8 a2[4];
    {
        int rw = w * 16 + lm;
#pragma unroll
        for (int kk = 0; kk < 4; ++kk) {
            int byte = (rw * 256 + kk * 64 + lg * 16) ^ ((rw & 7) << 4);
            a2[kk] = *(const short8*)(smem + 32768 + byte);
        }
    }
    __syncthreads();

    f32x4 acc2[8];
#pragma unroll
    for (int nt = 0; nt < 8; ++nt) {
        f32x4 c = {0.f, 0.f, 0.f, 0.f};
#pragma unroll
        for (int kk = 0; kk < 4; ++kk) {
            int nrow = nt * 16 + lm;
            int byte = (nrow * 256 + kk * 64 + lg * 16) ^ ((nrow & 7) << 4);
            short8 b = *(const short8*)(smem + byte);
            c = __builtin_amdgcn_mfma_f32_16x16x32_bf16(a2[kk], b, c, 0, 0, 0);
        }
        acc2[nt] = c;
    }

    float val[8][4];
#pragma unroll
    for (int nt = 0; nt < 8; ++nt)
#pragma unroll
        for (int j = 0; j < 4; ++j) val[nt][j] = acc2[nt][j] + b2v[nt];

    float mu[4], rs[4];
#pragma unroll
    for (int j = 0; j < 4; ++j) {
        float s = 0.f;
#pragma unroll
        for (int nt = 0; nt < 8; ++nt) s += val[nt][j];
        s += __shfl_xor(s, 1, 64); s += __shfl_xor(s, 2, 64);
        s += __shfl_xor(s, 4, 64); s += __shfl_xor(s, 8, 64);
        mu[j] = s * (1.f / 128.f);
        float d2 = 0.f;
#pragma unroll
        for (int nt = 0; nt < 8; ++nt) {
            float d = val[nt][j] - mu[j];
            d2 = fmaf(d, d, d2);
        }
        d2 += __shfl_xor(d2, 1, 64); d2 += __shfl_xor(d2, 2, 64);
        d2 += __shfl_xor(d2, 4, 64); d2 += __shfl_xor(d2, 8, 64);
        rs[j] = rsqrtf(d2 * (1.f / 128.f) + 1e-5f);
    }

#pragma unroll
    for (int j = 0; j < 4; ++j) {
        int grow = r0 + w * 16 + lg * 4 + j;
        if (grow < n) {
#pragma unroll
            for (int nt = 0; nt < 8; ++nt) {
                int col = nt * 16 + lm;
                size_t o = (size_t)grow * HIDDEN + col;
                float y = fmaxf((val[nt][j] - mu[j]) * rs[j] * lngv[nt] + lnbv[nt], 0.f) + h32[o];
                h32[o] = y;
                h16[o] = f2bf(y);
            }
        }
    }
}

// ---------------- launch ----------------

extern "C" void kernel_launch(void* const* d_in, const int* in_sizes, int n_in,
                              void* d_out, int out_size, void* d_ws, size_t ws_size,
                              hipStream_t stream) {
    const float* x     = (const float*)d_in[0];
    const int*   ei    = (const int*)d_in[2];
    const float* eattr = (const float*)d_in[3];
    const float* We    = (const float*)d_in[4];
    const float* be    = (const float*)d_in[5];
    const float* W1    = (const float*)d_in[6];
    const float* b1    = (const float*)d_in[7];
    const float* W2    = (const float*)d_in[8];
    const float* b2    = (const float*)d_in[9];
    const float* lng   = (const float*)d_in[10];
    const float* lnb   = (const float*)d_in[11];
    float* h32 = (float*)d_out;

    const int n = in_sizes[0] / HIDDEN;
    const int E = in_sizes[2] / 2;
    const int* src = ei;
    const int* dst = ei + E;

    size_t off = 0;
    auto take = [&](size_t bytes) {
        void* p = (char*)d_ws + off;
        off += (bytes + 255) & ~(size_t)255;
        return p;
    };
    ushort* z0      = (ushort*)take((size_t)n * HIDDEN * 2);
    ushort* h16     = (ushort*)take((size_t)n * HIDDEN * 2);
    ushort* Wt      = (ushort*)take((size_t)NLAYERS * 2 * HIDDEN * HIDDEN * 2);
    int*    counts  = (int*)take((size_t)n * 4);
    int*    offsets = (int*)take(((size_t)n + 1) * 4);
    int*    wpos    = (int*)take((size_t)n * 4);
    int2*   csr     = (int2*)take((size_t)E * 8);
    const size_t ea_bytes = (size_t)E * HIDDEN * 2;
    const bool use_ea = (off + ea_bytes) <= ws_size;
    ushort* ea_csr = use_ea ? (ushort*)take(ea_bytes) : nullptr;

    hipMemcpyAsync(h32, x, (size_t)n * HIDDEN * 4, hipMemcpyDeviceToDevice, stream);
    h16init_kernel<<<((n * HIDDEN / 4) + 255) / 256, 256, 0, stream>>>(x, h16, n * HIDDEN / 4);
    wconv_kernel<<<(NLAYERS * 2 * HIDDEN * HIDDEN) / 256, 256, 0, stream>>>(W1, W2, Wt);

    hipMemsetAsync(counts, 0, (size_t)n * 4, stream);
    int eb = (E + 255) / 256;
    hist_kernel<<<eb, 256, 0, stream>>>(dst, counts, E);
    scan_kernel<<<1, 1024, 0, stream>>>(counts, offsets, wpos, n);
    fill_kernel<<<eb, 256, 0, stream>>>(src, dst, wpos, csr, E);
    if (use_ea)
        ea_kernel<<<(E + 255) / 256, 256, 0, stream>>>(csr, eattr, We, be, ea_csr, E);

    for (int lyr = 0; lyr < NLAYERS; ++lyr) {
        if (use_ea)
            agg_kernel<<<(n + 3) / 4, 256, 0, stream>>>(h16, h32, csr, ea_csr, offsets, z0, n);
        else
            agg_fb_kernel<<<(n + 1) / 2, 128, 0, stream>>>(h16, h32, csr, eattr, offsets,
                                                           We, be, z0, n);
        mlp_kernel<<<(n + 63) / 64, 256, 0, stream>>>(z0, h32, h16,
                                                      Wt + (size_t)(lyr * 2 + 0) * 16384,
                                                      Wt + (size_t)(lyr * 2 + 1) * 16384,
                                                      b1 + (size_t)lyr * HIDDEN,
                                                      b2 + (size_t)lyr * HIDDEN,
                                                      lng + (size_t)lyr * HIDDEN,
                                                      lnb + (size_t)lyr * HIDDEN, n);
    }
}

// Round 4
// 495.002 us; speedup vs baseline: 2.0341x; 1.0545x over previous
//
#include <hip/hip_runtime.h>

#define HIDDEN 128
#define NLAYERS 4

typedef __attribute__((ext_vector_type(8))) short short8;
typedef __attribute__((ext_vector_type(4))) float f32x4;

__device__ __forceinline__ ushort f2bf(float f) {
    uint x = __builtin_bit_cast(uint, f);
    return (ushort)((x + 0x7fffu + ((x >> 16) & 1u)) >> 16);
}
__device__ __forceinline__ float bf2f(ushort u) {
    uint x = ((uint)u) << 16;
    return __builtin_bit_cast(float, x);
}
__device__ __forceinline__ float bflo(uint u) {
    return __builtin_bit_cast(float, u << 16);
}
__device__ __forceinline__ float bfhi(uint u) {
    return __builtin_bit_cast(float, u & 0xffff0000u);
}

// ---------------- CSR build ----------------

__global__ void hist_kernel(const int* __restrict__ dst, int* __restrict__ counts, int E) {
    int e = blockIdx.x * blockDim.x + threadIdx.x;
    if (e < E) atomicAdd(&counts[dst[e]], 1);
}

__global__ __launch_bounds__(1024) void scan_kernel(const int* __restrict__ counts,
                                                    int* __restrict__ offsets,
                                                    int* __restrict__ wpos, int n) {
    __shared__ int wsum[16];
    __shared__ int carry_s;
    const int t = threadIdx.x, wv = t >> 6, ln = t & 63;
    if (t == 0) carry_s = 0;
    __syncthreads();
    for (int base = 0; base < n; base += 1024) {
        int i = base + t;
        int v = (i < n) ? counts[i] : 0;
        int s = v;
#pragma unroll
        for (int off = 1; off < 64; off <<= 1) {
            int x = __shfl_up(s, off, 64);
            if (ln >= off) s += x;
        }
        if (ln == 63) wsum[wv] = s;
        __syncthreads();
        if (t < 16) {
            int x = wsum[t];
#pragma unroll
            for (int off = 1; off < 16; off <<= 1) {
                int y = __shfl_up(x, off, 16);
                if ((t & 15) >= off) x += y;
            }
            wsum[t] = x;
        }
        __syncthreads();
        int wbase = (wv ? wsum[wv - 1] : 0) + carry_s;
        int excl = wbase + s - v;
        if (i < n) { offsets[i] = excl; wpos[i] = excl; }
        __syncthreads();
        if (t == 0) carry_s += wsum[15];
        __syncthreads();
    }
    if (t == 0) offsets[n] = carry_s;
}

__global__ void fill_kernel(const int* __restrict__ src, const int* __restrict__ dst,
                            int* __restrict__ wpos, int* __restrict__ csr_src,
                            int* __restrict__ csr_eid, int E) {
    int e = blockIdx.x * blockDim.x + threadIdx.x;
    if (e < E) {
        int d = dst[e];
        int p = atomicAdd(&wpos[d], 1);
        csr_src[p] = src[e];
        csr_eid[p] = e;
    }
}

// ---------------- init / weight prep ----------------

__global__ void h16init_kernel(const float* __restrict__ x, ushort* __restrict__ h16, int total4) {
    int i = blockIdx.x * blockDim.x + threadIdx.x;
    if (i < total4) {
        float4 v = ((const float4*)x)[i];
        uint2 o;
        o.x = (uint)f2bf(v.x) | ((uint)f2bf(v.y) << 16);
        o.y = (uint)f2bf(v.z) | ((uint)f2bf(v.w) << 16);
        ((uint2*)h16)[i] = o;
    }
}

__global__ void wconv_kernel(const float* __restrict__ W1, const float* __restrict__ W2,
                             ushort* __restrict__ Wt) {
    int i = blockIdx.x * blockDim.x + threadIdx.x;  // < 4*2*128*128
    int l = i >> 15;
    int m = (i >> 14) & 1;
    int nn = (i >> 7) & 127;
    int kk = i & 127;
    const float* W = m ? W2 : W1;
    Wt[i] = f2bf(W[l * 16384 + kk * 128 + nn]);
}

#define EA_FMA16(q0, q1, q2, q3)                                          \
    m0 = fmaf(q0.x, wec[0].x, m0);  m1 = fmaf(q0.x, wec[0].y, m1);        \
    m0 = fmaf(q0.y, wec[1].x, m0);  m1 = fmaf(q0.y, wec[1].y, m1);        \
    m0 = fmaf(q0.z, wec[2].x, m0);  m1 = fmaf(q0.z, wec[2].y, m1);        \
    m0 = fmaf(q0.w, wec[3].x, m0);  m1 = fmaf(q0.w, wec[3].y, m1);        \
    m0 = fmaf(q1.x, wec[4].x, m0);  m1 = fmaf(q1.x, wec[4].y, m1);        \
    m0 = fmaf(q1.y, wec[5].x, m0);  m1 = fmaf(q1.y, wec[5].y, m1);        \
    m0 = fmaf(q1.z, wec[6].x, m0);  m1 = fmaf(q1.z, wec[6].y, m1);        \
    m0 = fmaf(q1.w, wec[7].x, m0);  m1 = fmaf(q1.w, wec[7].y, m1);        \
    m0 = fmaf(q2.x, wec[8].x, m0);  m1 = fmaf(q2.x, wec[8].y, m1);        \
    m0 = fmaf(q2.y, wec[9].x, m0);  m1 = fmaf(q2.y, wec[9].y, m1);        \
    m0 = fmaf(q2.z, wec[10].x, m0); m1 = fmaf(q2.z, wec[10].y, m1);       \
    m0 = fmaf(q2.w, wec[11].x, m0); m1 = fmaf(q2.w, wec[11].y, m1);       \
    m0 = fmaf(q3.x, wec[12].x, m0); m1 = fmaf(q3.x, wec[12].y, m1);       \
    m0 = fmaf(q3.y, wec[13].x, m0); m1 = fmaf(q3.y, wec[13].y, m1);       \
    m0 = fmaf(q3.z, wec[14].x, m0); m1 = fmaf(q3.z, wec[14].y, m1);       \
    m0 = fmaf(q3.w, wec[15].x, m0); m1 = fmaf(q3.w, wec[15].y, m1)

// ---------------- ea precompute (CSR order) ----------------
__global__ __launch_bounds__(256) void ea_kernel(const int* __restrict__ csr_eid,
                                                 const float* __restrict__ edge_attr,
                                                 const float* __restrict__ We,
                                                 const float* __restrict__ be,
                                                 ushort* __restrict__ ea_csr, int E) {
    __shared__ int eids[256];
    __shared__ float4 ear[256][4];
    const int t = threadIdx.x, l = t & 63, w = t >> 6;
    const int c0 = l * 2;
    float2 wec[16];
#pragma unroll
    for (int k = 0; k < 16; ++k) wec[k] = *(const float2*)(We + k * HIDDEN + c0);
    const float2 bec = *(const float2*)(be + c0);
    const int p0 = blockIdx.x * 256;

    eids[t] = (p0 + t < E) ? csr_eid[p0 + t] : 0;
    __syncthreads();
#pragma unroll
    for (int k = 0; k < 4; ++k) {
        int e = (t >> 2) + k * 64;
        int part = t & 3;
        if (p0 + e < E)
            ear[e][part] = ((const float4*)edge_attr)[(size_t)eids[e] * 4 + part];
    }
    __syncthreads();

    for (int j = 0; j < 64; ++j) {
        int e = w * 64 + j;
        int p = p0 + e;
        if (p >= E) break;
        float4 q0 = ear[e][0], q1 = ear[e][1], q2 = ear[e][2], q3 = ear[e][3];
        float m0 = bec.x, m1 = bec.y;
        EA_FMA16(q0, q1, q2, q3);
        uint out = (uint)f2bf(m0) | ((uint)f2bf(m1) << 16);
        *(uint*)(ea_csr + (size_t)p * HIDDEN + c0) = out;
    }
}

// ---------------- aggregation: wave/node, 16-lane group per edge, uint4 rows ----------------
__global__ __launch_bounds__(256) void agg_kernel(const ushort* __restrict__ h16,
                                                  const float* __restrict__ h32,
                                                  const int* __restrict__ csr_src,
                                                  const ushort* __restrict__ ea_csr,
                                                  const int* __restrict__ offsets,
                                                  ushort* __restrict__ z0, int n) {
    const int v = blockIdx.x * 4 + (threadIdx.x >> 6);
    if (v >= n) return;
    const int l = threadIdx.x & 63;
    const int g = l >> 4, q = l & 15;

    const int e0 = offsets[v], e1 = offsets[v + 1];
    float acc[8];
#pragma unroll
    for (int i = 0; i < 8; ++i) acc[i] = 0.f;

#pragma unroll 2
    for (int it = e0; it < e1; it += 4) {
        const int e = it + g;
        const float vm = (e < e1) ? 1.f : 0.f;
        const int ec = (e < e1) ? e : (e1 - 1);
        const int s = csr_src[ec];
        const uint4 ev = *(const uint4*)(ea_csr + (size_t)ec * HIDDEN + q * 8);
        const uint4 hv = *(const uint4*)(h16 + (size_t)s * HIDDEN + q * 8);
#define ACC2(i, ue, uh)                                                   \
        {                                                                 \
            float s0 = bflo(ue) + bflo(uh);                               \
            float s1 = bfhi(ue) + bfhi(uh);                               \
            acc[2*(i)]   = fmaf(vm, fmaxf(s0, 0.f), acc[2*(i)]);          \
            acc[2*(i)+1] = fmaf(vm, fmaxf(s1, 0.f), acc[2*(i)+1]);        \
        }
        ACC2(0, ev.x, hv.x) ACC2(1, ev.y, hv.y) ACC2(2, ev.z, hv.z) ACC2(3, ev.w, hv.w)
#undef ACC2
    }

    // reduce across the 4 groups
#pragma unroll
    for (int i = 0; i < 8; ++i) {
        acc[i] += __shfl_xor(acc[i], 16, 64);
        acc[i] += __shfl_xor(acc[i], 32, 64);
    }

    if (g == 0) {
        const float* hp = h32 + (size_t)v * HIDDEN + q * 8;
        const float4 h0 = *(const float4*)hp;
        const float4 h1 = *(const float4*)(hp + 4);
        uint4 o;
        o.x = (uint)f2bf(h0.x + acc[0]) | ((uint)f2bf(h0.y + acc[1]) << 16);
        o.y = (uint)f2bf(h0.z + acc[2]) | ((uint)f2bf(h0.w + acc[3]) << 16);
        o.z = (uint)f2bf(h1.x + acc[4]) | ((uint)f2bf(h1.y + acc[5]) << 16);
        o.w = (uint)f2bf(h1.z + acc[6]) | ((uint)f2bf(h1.w + acc[7]) << 16);
        *(uint4*)(z0 + (size_t)v * HIDDEN + q * 8) = o;
    }
}

// ---------------- fallback aggregation (recompute ea per edge) ----------------
__global__ __launch_bounds__(128) void agg_fb_kernel(const ushort* __restrict__ h16,
                                                     const float* __restrict__ h32,
                                                     const int* __restrict__ csr_src,
                                                     const int* __restrict__ csr_eid,
                                                     const float* __restrict__ edge_attr,
                                                     const int* __restrict__ offsets,
                                                     const float* __restrict__ We,
                                                     const float* __restrict__ be,
                                                     ushort* __restrict__ z0, int n) {
    const int v = blockIdx.x * 2 + (threadIdx.x >> 6);
    if (v >= n) return;
    const int t = threadIdx.x & 63;
    const int c0 = t * 2;
    float2 wec[16];
#pragma unroll
    for (int k = 0; k < 16; ++k) wec[k] = *(const float2*)(We + k * HIDDEN + c0);
    const float2 bec = *(const float2*)(be + c0);

    const int e0 = offsets[v], e1 = offsets[v + 1];
    float a0 = 0.f, a1 = 0.f;
    for (int j = e0; j < e1; ++j) {
        int se = csr_src[j], eid = csr_eid[j];
        const float4* ea4 = (const float4*)(edge_attr + (size_t)eid * 16);
        float4 q0 = ea4[0], q1 = ea4[1], q2 = ea4[2], q3 = ea4[3];
        float m0 = bec.x, m1 = bec.y;
        EA_FMA16(q0, q1, q2, q3);
        uint hh = *(const uint*)(h16 + (size_t)se * HIDDEN + c0);
        a0 += fmaxf(m0 + bf2f((ushort)(hh & 0xffffu)), 0.f);
        a1 += fmaxf(m1 + bf2f((ushort)(hh >> 16)), 0.f);
    }
    const float2 hv = *(const float2*)(h32 + (size_t)v * HIDDEN + c0);
    uint out = (uint)f2bf(hv.x + a0) | ((uint)f2bf(hv.y + a1) << 16);
    *(uint*)(z0 + (size_t)v * HIDDEN + c0) = out;
}

// ---------------- fused MFMA MLP + in-register LayerNorm + residual ----------------
__global__ __launch_bounds__(256, 3) void mlp_kernel(const ushort* __restrict__ z0,
                                                     float* __restrict__ h32,
                                                     ushort* __restrict__ h16,
                                                     const ushort* __restrict__ W1t,
                                                     const ushort* __restrict__ W2t,
                                                     const float* __restrict__ b1,
                                                     const float* __restrict__ b2,
                                                     const float* __restrict__ lng,
                                                     const float* __restrict__ lnb, int n) {
    __shared__ char smem[49152];  // [0,32K): weights (swizzled bf16) ; [32K,48K): act
    const int t = threadIdx.x, l = t & 63, w = t >> 6;
    const int lm = l & 15, lg = l >> 4;
    const int r0 = blockIdx.x * 64;

#pragma unroll
    for (int j = 0; j < 8; ++j) {
        int idx = t + j * 256;
        int byte = (idx * 16) ^ (((idx >> 4) & 7) << 4);
        *(short8*)(smem + byte) = *(const short8*)(W1t + idx * 8);
    }

    float b1v[8], b2v[8], lngv[8], lnbv[8];
#pragma unroll
    for (int nt = 0; nt < 8; ++nt) {
        int col = nt * 16 + lm;
        b1v[nt] = b1[col]; b2v[nt] = b2[col];
        lngv[nt] = lng[col]; lnbv[nt] = lnb[col];
    }

    short8 a[4];
    {
        int arow = r0 + w * 16 + lm;
        if (arow >= n) arow = n - 1;
        const ushort* zp = z0 + (size_t)arow * HIDDEN + lg * 8;
#pragma unroll
        for (int kk = 0; kk < 4; ++kk) a[kk] = *(const short8*)(zp + kk * 32);
    }
    __syncthreads();

    f32x4 acc[8];
#pragma unroll
    for (int nt = 0; nt < 8; ++nt) {
        f32x4 c = {0.f, 0.f, 0.f, 0.f};
#pragma unroll
        for (int kk = 0; kk < 4; ++kk) {
            int nrow = nt * 16 + lm;
            int byte = (nrow * 256 + kk * 64 + lg * 16) ^ ((nrow & 7) << 4);
            short8 b = *(const short8*)(smem + byte);
            c = __builtin_amdgcn_mfma_f32_16x16x32_bf16(a[kk], b, c, 0, 0, 0);
        }
        acc[nt] = c;
    }

#pragma unroll
    for (int nt = 0; nt < 8; ++nt) {
        int col = nt * 16 + lm;
#pragma unroll
        for (int j = 0; j < 4; ++j) {
            int rw = w * 16 + lg * 4 + j;
            int byte = (rw * 256 + col * 2) ^ ((rw & 7) << 4);
            *(ushort*)(smem + 32768 + byte) = f2bf(fmaxf(acc[nt][j] + b1v[nt], 0.f));
        }
    }
    __syncthreads();

#pragma unroll
    for (int j = 0; j < 8; ++j) {
        int idx = t + j * 256;
        int byte = (idx * 16) ^ (((idx >> 4) & 7) << 4);
        *(short8*)(smem + byte) = *(const short8*)(W2t + idx * 8);
    }
    short8 a2[4];
    {
        int rw = w * 16 + lm;
#pragma unroll
        for (int kk = 0; kk < 4; ++kk) {
            int byte = (rw * 256 + kk * 64 + lg * 16) ^ ((rw & 7) << 4);
            a2[kk] = *(const short8*)(smem + 32768 + byte);
        }
    }
    __syncthreads();

    f32x4 acc2[8];
#pragma unroll
    for (int nt = 0; nt < 8; ++nt) {
        f32x4 c = {0.f, 0.f, 0.f, 0.f};
#pragma unroll
        for (int kk = 0; kk < 4; ++kk) {
            int nrow = nt * 16 + lm;
            int byte = (nrow * 256 + kk * 64 + lg * 16) ^ ((nrow & 7) << 4);
            short8 b = *(const short8*)(smem + byte);
            c = __builtin_amdgcn_mfma_f32_16x16x32_bf16(a2[kk], b, c, 0, 0, 0);
        }
        acc2[nt] = c;
    }

    float val[8][4];
#pragma unroll
    for (int nt = 0; nt < 8; ++nt)
#pragma unroll
        for (int j = 0; j < 4; ++j) val[nt][j] = acc2[nt][j] + b2v[nt];

    float mu[4], rs[4];
#pragma unroll
    for (int j = 0; j < 4; ++j) {
        float s = 0.f;
#pragma unroll
        for (int nt = 0; nt < 8; ++nt) s += val[nt][j];
        s += __shfl_xor(s, 1, 64); s += __shfl_xor(s, 2, 64);
        s += __shfl_xor(s, 4, 64); s += __shfl_xor(s, 8, 64);
        mu[j] = s * (1.f / 128.f);
        float d2 = 0.f;
#pragma unroll
        for (int nt = 0; nt < 8; ++nt) {
            float d = val[nt][j] - mu[j];
            d2 = fmaf(d, d, d2);
        }
        d2 += __shfl_xor(d2, 1, 64); d2 += __shfl_xor(d2, 2, 64);
        d2 += __shfl_xor(d2, 4, 64); d2 += __shfl_xor(d2, 8, 64);
        rs[j] = rsqrtf(d2 * (1.f / 128.f) + 1e-5f);
    }

#pragma unroll
    for (int j = 0; j < 4; ++j) {
        int grow = r0 + w * 16 + lg * 4 + j;
        if (grow < n) {
#pragma unroll
            for (int nt = 0; nt < 8; ++nt) {
                int col = nt * 16 + lm;
                size_t o = (size_t)grow * HIDDEN + col;
                float y = fmaxf((val[nt][j] - mu[j]) * rs[j] * lngv[nt] + lnbv[nt], 0.f) + h32[o];
                h32[o] = y;
                h16[o] = f2bf(y);
            }
        }
    }
}

// ---------------- launch ----------------

extern "C" void kernel_launch(void* const* d_in, const int* in_sizes, int n_in,
                              void* d_out, int out_size, void* d_ws, size_t ws_size,
                              hipStream_t stream) {
    const float* x     = (const float*)d_in[0];
    const int*   ei    = (const int*)d_in[2];
    const float* eattr = (const float*)d_in[3];
    const float* We    = (const float*)d_in[4];
    const float* be    = (const float*)d_in[5];
    const float* W1    = (const float*)d_in[6];
    const float* b1    = (const float*)d_in[7];
    const float* W2    = (const float*)d_in[8];
    const float* b2    = (const float*)d_in[9];
    const float* lng   = (const float*)d_in[10];
    const float* lnb   = (const float*)d_in[11];
    float* h32 = (float*)d_out;

    const int n = in_sizes[0] / HIDDEN;
    const int E = in_sizes[2] / 2;
    const int* src = ei;
    const int* dst = ei + E;

    size_t off = 0;
    auto take = [&](size_t bytes) {
        void* p = (char*)d_ws + off;
        off += (bytes + 255) & ~(size_t)255;
        return p;
    };
    ushort* z0      = (ushort*)take((size_t)n * HIDDEN * 2);
    ushort* h16     = (ushort*)take((size_t)n * HIDDEN * 2);
    ushort* Wt      = (ushort*)take((size_t)NLAYERS * 2 * HIDDEN * HIDDEN * 2);
    int*    counts  = (int*)take((size_t)n * 4);
    int*    offsets = (int*)take(((size_t)n + 1) * 4);
    int*    wpos    = (int*)take((size_t)n * 4);
    int*    csr_src = (int*)take((size_t)E * 4);
    int*    csr_eid = (int*)take((size_t)E * 4);
    const size_t ea_bytes = (size_t)E * HIDDEN * 2;
    const bool use_ea = (off + ea_bytes) <= ws_size;
    ushort* ea_csr = use_ea ? (ushort*)take(ea_bytes) : nullptr;

    hipMemcpyAsync(h32, x, (size_t)n * HIDDEN * 4, hipMemcpyDeviceToDevice, stream);
    h16init_kernel<<<((n * HIDDEN / 4) + 255) / 256, 256, 0, stream>>>(x, h16, n * HIDDEN / 4);
    wconv_kernel<<<(NLAYERS * 2 * HIDDEN * HIDDEN) / 256, 256, 0, stream>>>(W1, W2, Wt);

    hipMemsetAsync(counts, 0, (size_t)n * 4, stream);
    int eb = (E + 255) / 256;
    hist_kernel<<<eb, 256, 0, stream>>>(dst, counts, E);
    scan_kernel<<<1, 1024, 0, stream>>>(counts, offsets, wpos, n);
    fill_kernel<<<eb, 256, 0, stream>>>(src, dst, wpos, csr_src, csr_eid, E);
    if (use_ea)
        ea_kernel<<<(E + 255) / 256, 256, 0, stream>>>(csr_eid, eattr, We, be, ea_csr, E);

    for (int lyr = 0; lyr < NLAYERS; ++lyr) {
        if (use_ea)
            agg_kernel<<<(n + 3) / 4, 256, 0, stream>>>(h16, h32, csr_src, ea_csr, offsets, z0, n);
        else
            agg_fb_kernel<<<(n + 1) / 2, 128, 0, stream>>>(h16, h32, csr_src, csr_eid, eattr,
                                                           offsets, We, be, z0, n);
        mlp_kernel<<<(n + 63) / 64, 256, 0, stream>>>(z0, h32, h16,
                                                      Wt + (size_t)(lyr * 2 + 0) * 16384,
                                                      Wt + (size_t)(lyr * 2 + 1) * 16384,
                                                      b1 + (size_t)lyr * HIDDEN,
                                                      b2 + (size_t)lyr * HIDDEN,
                                                      lng + (size_t)lyr * HIDDEN,
                                                      lnb + (size_t)lyr * HIDDEN, n);
    }
}